// Round 13
// baseline (100.861 us; speedup 1.0000x reference)
//
#include <hip/hip_runtime.h>
#include <hip/hip_bf16.h>
#include <math.h>

// SupCon loss, N=8192 D=128 fp32 in, scalar fp32 out.
// Round 16: occupancy, done right this time. R15's null (extra prefetch cover
// changed nothing) kills per-load latency as the wall; remaining suspect is
// wave-level starvation at 2 waves/SIMD (192 unified regs/wave). R11/R12's
// 512-thread reshapes failed in the ALLOCATOR, not the arithmetic. This round:
// 256-thread blocks (allocator-friendly all session) with 32x64 wave tiles:
// 2048 blocks = 64 ti x 2 half x 16 g. Per-wave state: acc 32 + Af 32 +
// bf-dbuf 32 + RE/RP 16 + li 8 + misc ~20 = ~148 regs -> 3 waves/SIMD
// (launch_bounds(256,3) caps at 170, margin 22). Cost: B-frag L2 traffic 2x
// (~512 MB ~ 15us at L2 BW) -- the run discriminates latency-bound (big win)
// vs L2-BW-bound (flat). R14/R15 software pipeline, poison algebra, private
// slots [N][32], prep, reduce all verbatim. Spill tripwire: sim in top-5 with
// WRITE_SIZE >> 3 MB.

constexpr int N = 8192;
constexpr int D = 128;

typedef __attribute__((ext_vector_type(8))) short short8;  // 8 bf16 = 4 VGPRs
typedef __attribute__((ext_vector_type(4))) float f32x4;

constexpr float SELF_POISON = -50.0f;  // exp2(-50) ~ 9e-16; |s2| <= 14.43 real

__device__ __forceinline__ float fast_exp2(float x) {
#if __has_builtin(__builtin_amdgcn_exp2f)
    return __builtin_amdgcn_exp2f(x);
#else
    return __expf(x * 0.69314718056f);
#endif
}

// ---------------- prep: bf16 rows scaled into log2 domain, fragment layout --
// FbP uint index for element pair (row, k=2l): (row>>4)*1024 + (l>>2)*64 +
// (row&15)*4 + (l&3). Chunk chi = l>>2 holds k = 8*chi .. 8*chi+7 in order.
// Also zeroes out[0] (stream-ordered before reduce's atomicAdd).
__global__ void prep_kernel(const float* __restrict__ F,
                            unsigned int* __restrict__ FbP,
                            float* __restrict__ out) {
    if (blockIdx.x == 0 && threadIdx.x == 0) out[0] = 0.0f;
    int row = blockIdx.x * 4 + (threadIdx.x >> 6);
    int l = threadIdx.x & 63;
    float2 v = ((const float2*)(F + (size_t)row * D))[l];
    float ss = v.x * v.x + v.y * v.y;
#pragma unroll
    for (int off = 32; off > 0; off >>= 1) ss += __shfl_xor(ss, off);
    float sc = sqrtf(14.4269504089f / ss);  // 10 * log2(e), folded
    __hip_bfloat16 hx = __float2bfloat16(v.x * sc);
    __hip_bfloat16 hy = __float2bfloat16(v.y * sc);
    unsigned int ux = *(unsigned short*)&hx;
    unsigned int uy = *(unsigned short*)&hy;
    unsigned int idx = ((unsigned)(row >> 4) << 10) | ((unsigned)(l >> 2) << 6) |
                       ((unsigned)(row & 15) << 2) | (unsigned)(l & 3);
    FbP[idx] = ux | (uy << 16);
}

// ---------------- sim: full matrix, MFMA, no LDS/barriers/atomics -----------
// 2048 blocks: (ti, half, g). Block covers rows i0..i0+63 (i0 = ti*128 +
// half*64) x col-tiles tj in [4g, 4g+3]. 4 waves: (ry, cx) each 32x64.
#define LOADB(BUF, TJ, KK)                                          \
    _Pragma("unroll") for (int n_ = 0; n_ < 4; ++n_)                \
        BUF[n_] = P[((TJ) * 8 + cx * 4 + n_) * 256 + (KK) * 64 + l];

#define MFMASTEP(BUF, KK)                                           \
    _Pragma("unroll") for (int m_ = 0; m_ < 2; ++m_)                \
        _Pragma("unroll") for (int n_ = 0; n_ < 4; ++n_)            \
            acc[m_][n_] = __builtin_amdgcn_mfma_f32_16x16x32_bf16(  \
                Af[KK][m_], BUF[n_], acc[m_][n_], 0, 0, 0);

__global__ __launch_bounds__(256, 3) void sim_kernel(
    const short8* __restrict__ P, const int* __restrict__ labels,
    float* __restrict__ partE, float* __restrict__ partP) {
    const int ti   = blockIdx.x >> 5;         // 64 row tiles
    const int rem  = blockIdx.x & 31;
    const int half = rem >> 4;                // 0/1: which 64-row half
    const int g    = rem & 15;                // 16 column groups
    const int tjs = g * 4;
    const int i0 = ti * 128 + half * 64;

    const int t = threadIdx.x, w = t >> 6, l = t & 63;
    const int c = l & 15, quad = l >> 4;    // MFMA lane split
    const int ry = w >> 1, cx = w & 1;      // 32x64 tile per wave

    // A fragments for the whole strip: 8 x 1KB coalesced loads, 32 VGPR.
    short8 Af[4][2];  // [kk][m]
#pragma unroll
    for (int kk = 0; kk < 4; ++kk)
#pragma unroll
        for (int m = 0; m < 2; ++m)
            Af[kk][m] = P[(ti * 8 + half * 4 + ry * 2 + m) * 256 + kk * 64 + l];

    // row labels for this wave's rows (strip-constant)
    int li[2][4];
#pragma unroll
    for (int m = 0; m < 2; ++m)
#pragma unroll
        for (int r = 0; r < 4; ++r)
            li[m][r] = labels[i0 + ry * 32 + m * 16 + quad * 4 + r];

    const bool selfQuad = (quad == (c >> 2));  // lane may hold self elements

    float RE[2][4] = {}, RP[2][4] = {};  // row partials, carried across strip

    short8 bfA[4], bfB[4];   // B-fragment double buffer (static indices only)
    LOADB(bfA, tjs, 0);      // prologue: kk0 and kk1 of first tile in flight
    LOADB(bfB, tjs, 1);

#pragma unroll 1
    for (int tj = tjs; tj < tjs + 4; ++tj) {
        const int j0 = tj * 128;
        int lj[4];
#pragma unroll
        for (int n = 0; n < 4; ++n) lj[n] = labels[j0 + cx * 64 + n * 16 + c];

        f32x4 acc[2][4] = {};
        const int tp = (tj < tjs + 3) ? tj + 1 : tjs;  // last prefetch harmless
        // steady state: bfA=kk0, bfB=kk1 already in flight (epilogue-covered)
        MFMASTEP(bfA, 0);
        LOADB(bfA, tj, 2);
        MFMASTEP(bfB, 1);
        LOADB(bfB, tj, 3);
        MFMASTEP(bfA, 2);
        LOADB(bfA, tp, 0);
        MFMASTEP(bfB, 3);
        LOADB(bfB, tp, 1);   // next tile's kk1 also rides under the epilogue

        // Diagonal tile: poison self elements. Self iff tj==ti && cx==half &&
        // n == ry*2+m && c == quad*4+r.
        if (tj == ti && cx == half) {
            const int ns = ry * 2;
#pragma unroll
            for (int m = 0; m < 2; ++m)
#pragma unroll
                for (int r = 0; r < 4; ++r) {
                    bool cond = selfQuad && (r == (c & 3));
                    acc[m][ns + m][r] = cond ? SELF_POISON : acc[m][ns + m][r];
                }
        }

        // ---- minimal row-only epilogue: 5 insts per element ----
        // (covers the latency of the two next-tile prefetches above)
#pragma unroll
        for (int m = 0; m < 2; ++m) {
#pragma unroll
            for (int n = 0; n < 4; ++n) {
#pragma unroll
                for (int r = 0; r < 4; ++r) {
                    float s2 = acc[m][n][r];
                    RE[m][r] += fast_exp2(s2);
                    RP[m][r] += (li[m][r] == lj[n]) ? s2 : 0.0f;
                }
            }
        }
    }

    // strip end: row reduction across the 16 col-lanes, then PLAIN STORES to
    // this block+wave's private slice. No atomics anywhere in this kernel.
#pragma unroll
    for (int m = 0; m < 2; ++m)
#pragma unroll
        for (int r = 0; r < 4; ++r) {
#pragma unroll
            for (int off = 1; off < 16; off <<= 1) {
                RE[m][r] += __shfl_xor(RE[m][r], off);
                RP[m][r] += __shfl_xor(RP[m][r], off);
            }
        }
    if (c == 0) {
        // undo the diag poison injected into the positive-sums: exactly one
        // -50 per (m,r) in the cx==half waves of diag-containing blocks.
        if (g == (ti >> 2) && cx == half) {
#pragma unroll
            for (int m = 0; m < 2; ++m)
#pragma unroll
                for (int r = 0; r < 4; ++r) RP[m][r] -= SELF_POISON;
        }
        const int slot = g * 2 + cx;  // 32 private slots per row
#pragma unroll
        for (int m = 0; m < 2; ++m)
#pragma unroll
            for (int r = 0; r < 4; ++r) {
                int gi = i0 + ry * 32 + m * 16 + quad * 4 + r;
                partE[(size_t)gi * 32 + slot] = RE[m][r];
                partP[(size_t)gi * 32 + slot] = RP[m][r];
            }
    }
}

// ---------------- reduce: 128 blocks; one row per 32-lane half-wave ---------
// Builds the label histogram in LDS, sums the 32 partials per row, one scaled
// atomicAdd per block into out[0].
__global__ void reduce_kernel(const float* __restrict__ partE,
                              const float* __restrict__ partP,
                              const int* __restrict__ labels,
                              float* __restrict__ out) {
    __shared__ int hist[1024];
    __shared__ float ws4[4];
    const int t = threadIdx.x, w = t >> 6, l = t & 63;
    const int half = l >> 5, sl = l & 31;
    const int rbase = blockIdx.x * 64 + w * 16;  // 64 rows/block, 16/wave

#pragma unroll
    for (int k = 0; k < 4; ++k) hist[t + 256 * k] = 0;
    __syncthreads();
#pragma unroll
    for (int k = 0; k < 32; ++k) atomicAdd(&hist[labels[t + 256 * k]], 1);
    __syncthreads();

    float a = 0.0f;
#pragma unroll
    for (int it = 0; it < 8; ++it) {
        int row = rbase + it * 2 + half;
        float se = partE[(size_t)row * 32 + sl];
        float sp = partP[(size_t)row * 32 + sl];
#pragma unroll
        for (int off = 1; off < 32; off <<= 1) {
            se += __shfl_xor(se, off);
            sp += __shfl_xor(sp, off);
        }
        if (sl == 0) {
            int cnt = hist[labels[row]] - 1;
            if (cnt > 0)
                a += logf(se + 1e-9f) - 0.69314718056f * sp / (float)cnt;
        }
    }
    // wave reduce (only lanes sl==0 carry nonzero a)
#pragma unroll
    for (int off = 1; off < 64; off <<= 1) a += __shfl_xor(a, off);
    if (l == 0) ws4[w] = a;
    __syncthreads();
    if (t == 0) {
        float s = ws4[0] + ws4[1] + ws4[2] + ws4[3];
        atomicAdd(out, s * (1.0f / (float)N));
    }
}

extern "C" void kernel_launch(void* const* d_in, const int* in_sizes, int n_in,
                              void* d_out, int out_size, void* d_ws, size_t ws_size,
                              hipStream_t stream) {
    const float* F      = (const float*)d_in[0];
    const int*   labels = (const int*)d_in[1];
    float* out = (float*)d_out;

    unsigned int* FbP = (unsigned int*)d_ws;                         // 2 MB
    float* partE = (float*)((char*)d_ws + (size_t)2 * 1024 * 1024);  // 1 MB
    float* partP = partE + (size_t)N * 32;                           // 1 MB

    prep_kernel<<<N / 4, 256, 0, stream>>>(F, FbP, out);
    sim_kernel<<<2048, 256, 0, stream>>>((const short8*)FbP, labels, partE,
                                         partP);
    reduce_kernel<<<128, 256, 0, stream>>>(partE, partP, labels, out);
}

// Round 14
// 97.770 us; speedup vs baseline: 1.0316x; 1.0316x over previous
//
#include <hip/hip_runtime.h>
#include <hip/hip_bf16.h>
#include <math.h>

// SupCon loss, N=8192 D=128 fp32 in, scalar fp32 out.
// Round 17: sim's ~30us of idle is EXPOSED LOAD LATENCY: the 256MiB harness
// poison evicts the entire Infinity Cache each iteration and prep scatters
// FbP across all 8 XCDs' L2s, so sim's B-fragment loads are ~600-1500cyc,
// not ~200cyc L2 hits. Register-level batching can't cover that (R15 null:
// +2 loads of cover vs ~2400cyc/tile deficit; deeper buffers spill). Fix:
// global_load_lds double-buffered B-tile staging -- 32KB/tile in flight,
// issued one full tile (~1800cyc of MFMA+epilogue) ahead, fire-and-forget.
// Fragment-major layout makes each B-tile a CONTIGUOUS 32KB: staging is a
// linear lane-contiguous copy (no swizzle), ds_read_b128 conflict-free.
// bf double-buffer registers freed (-32) -> ~200 regs, proven-safe zone.
// Slim epilogue, poison algebra, private slots, prep/reduce: R15-verbatim.

constexpr int N = 8192;
constexpr int D = 128;

typedef __attribute__((ext_vector_type(8))) short short8;  // 8 bf16 = 4 VGPRs
typedef __attribute__((ext_vector_type(4))) float f32x4;

constexpr float SELF_POISON = -50.0f;  // exp2(-50) ~ 9e-16; |s2| <= 14.43 real

__device__ __forceinline__ float fast_exp2(float x) {
#if __has_builtin(__builtin_amdgcn_exp2f)
    return __builtin_amdgcn_exp2f(x);
#else
    return __expf(x * 0.69314718056f);
#endif
}

__device__ __forceinline__ void gload_lds16(const void* g, void* s) {
    __builtin_amdgcn_global_load_lds(
        (const __attribute__((address_space(1))) unsigned int*)g,
        (__attribute__((address_space(3))) unsigned int*)s, 16, 0, 0);
}

// ---------------- prep: bf16 rows scaled into log2 domain, fragment layout --
// FbP uint index for element pair (row, k=2l): (row>>4)*1024 + (l>>2)*64 +
// (row&15)*4 + (l&3). Chunk chi = l>>2 holds k = 8*chi .. 8*chi+7 in order.
// Also zeroes out[0] (stream-ordered before reduce's atomicAdd).
__global__ void prep_kernel(const float* __restrict__ F,
                            unsigned int* __restrict__ FbP,
                            float* __restrict__ out) {
    if (blockIdx.x == 0 && threadIdx.x == 0) out[0] = 0.0f;
    int row = blockIdx.x * 4 + (threadIdx.x >> 6);
    int l = threadIdx.x & 63;
    float2 v = ((const float2*)(F + (size_t)row * D))[l];
    float ss = v.x * v.x + v.y * v.y;
#pragma unroll
    for (int off = 32; off > 0; off >>= 1) ss += __shfl_xor(ss, off);
    float sc = sqrtf(14.4269504089f / ss);  // 10 * log2(e), folded
    __hip_bfloat16 hx = __float2bfloat16(v.x * sc);
    __hip_bfloat16 hy = __float2bfloat16(v.y * sc);
    unsigned int ux = *(unsigned short*)&hx;
    unsigned int uy = *(unsigned short*)&hy;
    unsigned int idx = ((unsigned)(row >> 4) << 10) | ((unsigned)(l >> 2) << 6) |
                       ((unsigned)(row & 15) << 2) | (unsigned)(l & 3);
    FbP[idx] = ux | (uy << 16);
}

// ---------------- sim: full matrix, MFMA, LDS-staged B, no atomics ----------
// Block (ti, g): A-frags in registers; B-tiles tj in [4g,4g+3] staged through
// a double-buffered LDS (32KB contiguous per tile in fragment-major layout).
// Stage of tile tj+1 is issued at the top of tile tj; the end-of-tile
// __syncthreads (vmcnt drain) is covered by tj's MFMA+epilogue.
__global__ __launch_bounds__(256, 2) void sim_kernel(
    const short8* __restrict__ P, const int* __restrict__ labels,
    float* __restrict__ partE, float* __restrict__ partP) {
    __shared__ short8 Bt[2][2048];  // 2 x 32 KB

    const int ti = blockIdx.x >> 4;   // 64 row tiles
    const int g  = blockIdx.x & 15;   // 16 column groups
    const int tjs = g * 4;
    const int i0 = ti * 128;

    const int t = threadIdx.x, w = t >> 6, l = t & 63;
    const int c = l & 15, quad = l >> 4;    // MFMA lane split
    const int wy = w >> 1, wx = w & 1;      // 64x64 quadrant per wave

    // A fragments for the whole strip: 16 x 1KB coalesced loads, 64 VGPR.
    short8 Af[4][4];  // [kk][m]
#pragma unroll
    for (int kk = 0; kk < 4; ++kk)
#pragma unroll
        for (int m = 0; m < 4; ++m)
            Af[kk][m] = P[(ti * 8 + wy * 4 + m) * 256 + kk * 64 + l];

    // row labels for this wave's rows (strip-constant)
    int li[4][4];
#pragma unroll
    for (int m = 0; m < 4; ++m)
#pragma unroll
        for (int r = 0; r < 4; ++r)
            li[m][r] = labels[i0 + wy * 64 + m * 16 + quad * 4 + r];

    const bool selfQuad = (quad == (c >> 2));  // lane may hold self elements

    // Stage one B tile (contiguous 32KB): wave w copies short8s
    // [w*512, w*512+512) in 8 lane-contiguous 1KB chunks.
#define STAGEB(BUF, TJ)                                                  \
    _Pragma("unroll") for (int it_ = 0; it_ < 8; ++it_)                  \
        gload_lds16(P + (size_t)(TJ) * 2048 + w * 512 + it_ * 64 + l,    \
                    &Bt[BUF][w * 512 + it_ * 64]);

    float RE[4][4] = {}, RP[4][4] = {};  // row partials, carried across strip

    STAGEB(0, tjs);        // prologue: first tile in flight
    __syncthreads();       // drain + gate (startup cost only)

#pragma unroll 1
    for (int tj = tjs; tj < tjs + 4; ++tj) {
        const int p = (tj - tjs) & 1;
        if (tj < tjs + 3) STAGEB(p ^ 1, tj + 1);  // fire-and-forget, 1 tile ahead

        const int j0 = tj * 128;
        int lj[4];
#pragma unroll
        for (int n = 0; n < 4; ++n) lj[n] = labels[j0 + wx * 64 + n * 16 + c];

        f32x4 acc[4][4] = {};
#pragma unroll
        for (int kk = 0; kk < 4; ++kk) {
            short8 bf[4];
#pragma unroll
            for (int n = 0; n < 4; ++n)
                bf[n] = Bt[p][(wx * 4 + n) * 256 + kk * 64 + l];
#pragma unroll
            for (int m = 0; m < 4; ++m)
#pragma unroll
                for (int n = 0; n < 4; ++n)
                    acc[m][n] = __builtin_amdgcn_mfma_f32_16x16x32_bf16(
                        Af[kk][m], bf[n], acc[m][n], 0, 0, 0);
        }

        // Diagonal tile: poison self elements so the clean epilogue naturally
        // zeroes them (exp2(-50)~0; the -50 entering RP is corrected at store).
        if (tj == ti && wy == wx) {
#pragma unroll
            for (int m = 0; m < 4; ++m)
#pragma unroll
                for (int r = 0; r < 4; ++r) {
                    bool cond = selfQuad && (r == (c & 3));
                    acc[m][m][r] = cond ? SELF_POISON : acc[m][m][r];
                }
        }

        // ---- minimal row-only epilogue: 5 insts per element ----
        // (covers the next tile's staging latency + the barrier drain)
#pragma unroll
        for (int m = 0; m < 4; ++m) {
#pragma unroll
            for (int n = 0; n < 4; ++n) {
#pragma unroll
                for (int r = 0; r < 4; ++r) {
                    float s2 = acc[m][n][r];
                    RE[m][r] += fast_exp2(s2);
                    RP[m][r] += (li[m][r] == lj[n]) ? s2 : 0.0f;
                }
            }
        }

        // drain this wave's stage-loads + gate buffer reuse: all waves done
        // reading Bt[p] before the next iteration stages into it.
        if (tj < tjs + 3) __syncthreads();
    }

    // strip end: row reduction across the 16 col-lanes, then PLAIN STORES to
    // this block+wave's private slice. No atomics anywhere in this kernel.
#pragma unroll
    for (int m = 0; m < 4; ++m)
#pragma unroll
        for (int r = 0; r < 4; ++r) {
#pragma unroll
            for (int off = 1; off < 16; off <<= 1) {
                RE[m][r] += __shfl_xor(RE[m][r], off);
                RP[m][r] += __shfl_xor(RP[m][r], off);
            }
        }
    if (c == 0) {
        // undo the diag poison injected into the positive-sums: exactly one
        // -50 per (m,r) row group in waves wy==wx of diag-containing blocks.
        if (g == (ti >> 2) && wy == wx) {
#pragma unroll
            for (int m = 0; m < 4; ++m)
#pragma unroll
                for (int r = 0; r < 4; ++r) RP[m][r] -= SELF_POISON;
        }
        const int slot = g * 2 + wx;  // 32 private slots per row
#pragma unroll
        for (int m = 0; m < 4; ++m)
#pragma unroll
            for (int r = 0; r < 4; ++r) {
                int gi = i0 + wy * 64 + m * 16 + quad * 4 + r;
                partE[(size_t)gi * 32 + slot] = RE[m][r];
                partP[(size_t)gi * 32 + slot] = RP[m][r];
            }
    }
}

// ---------------- reduce: 128 blocks; one row per 32-lane half-wave ---------
// Builds the label histogram in LDS, sums the 32 partials per row, one scaled
// atomicAdd per block into out[0].
__global__ void reduce_kernel(const float* __restrict__ partE,
                              const float* __restrict__ partP,
                              const int* __restrict__ labels,
                              float* __restrict__ out) {
    __shared__ int hist[1024];
    __shared__ float ws4[4];
    const int t = threadIdx.x, w = t >> 6, l = t & 63;
    const int half = l >> 5, sl = l & 31;
    const int rbase = blockIdx.x * 64 + w * 16;  // 64 rows/block, 16/wave

#pragma unroll
    for (int k = 0; k < 4; ++k) hist[t + 256 * k] = 0;
    __syncthreads();
#pragma unroll
    for (int k = 0; k < 32; ++k) atomicAdd(&hist[labels[t + 256 * k]], 1);
    __syncthreads();

    float a = 0.0f;
#pragma unroll
    for (int it = 0; it < 8; ++it) {
        int row = rbase + it * 2 + half;
        float se = partE[(size_t)row * 32 + sl];
        float sp = partP[(size_t)row * 32 + sl];
#pragma unroll
        for (int off = 1; off < 32; off <<= 1) {
            se += __shfl_xor(se, off);
            sp += __shfl_xor(sp, off);
        }
        if (sl == 0) {
            int cnt = hist[labels[row]] - 1;
            if (cnt > 0)
                a += logf(se + 1e-9f) - 0.69314718056f * sp / (float)cnt;
        }
    }
    // wave reduce (only lanes sl==0 carry nonzero a)
#pragma unroll
    for (int off = 1; off < 64; off <<= 1) a += __shfl_xor(a, off);
    if (l == 0) ws4[w] = a;
    __syncthreads();
    if (t == 0) {
        float s = ws4[0] + ws4[1] + ws4[2] + ws4[3];
        atomicAdd(out, s * (1.0f / (float)N));
    }
}

extern "C" void kernel_launch(void* const* d_in, const int* in_sizes, int n_in,
                              void* d_out, int out_size, void* d_ws, size_t ws_size,
                              hipStream_t stream) {
    const float* F      = (const float*)d_in[0];
    const int*   labels = (const int*)d_in[1];
    float* out = (float*)d_out;

    unsigned int* FbP = (unsigned int*)d_ws;                         // 2 MB
    float* partE = (float*)((char*)d_ws + (size_t)2 * 1024 * 1024);  // 1 MB
    float* partP = partE + (size_t)N * 32;                           // 1 MB

    prep_kernel<<<N / 4, 256, 0, stream>>>(F, FbP, out);
    sim_kernel<<<64 * 16, 256, 0, stream>>>((const short8*)FbP, labels, partE,
                                            partP);
    reduce_kernel<<<128, 256, 0, stream>>>(partE, partP, labels, out);
}

// Round 15
// 93.810 us; speedup vs baseline: 1.0752x; 1.0422x over previous
//
#include <hip/hip_runtime.h>
#include <hip/hip_bf16.h>
#include <math.h>

// SupCon loss, N=8192 D=128 fp32 in, scalar fp32 out.
// Round 18: three load-path implementations (reg pipeline R14/R15, LDS DMA
// R17) identical at sim~36.5us -> B-delivery is not the wall. Untested
// structure: per-block startup serialization (Af+labels loaded serially
// before any MFMA, x1024 blocks, hard 2-round boundary) and XCD locality
// (blocks sharing B-tiles scattered over all 8 XCDs). Fix, register-neutral:
// 512 blocks x 8 B-tiles each (startup + A-traffic halved, single residency
// round) + XCD-bijective bid = g2 + 8*ti so each B-group's 64 blocks land on
// one XCD (256KB of B-tiles become L2-local). Slots 32->16/row. R15 dbuf
// schedule, slim epilogue, poison algebra, prep verbatim.

constexpr int N = 8192;
constexpr int D = 128;

typedef __attribute__((ext_vector_type(8))) short short8;  // 8 bf16 = 4 VGPRs
typedef __attribute__((ext_vector_type(4))) float f32x4;

constexpr float SELF_POISON = -50.0f;  // exp2(-50) ~ 9e-16; |s2| <= 14.43 real

__device__ __forceinline__ float fast_exp2(float x) {
#if __has_builtin(__builtin_amdgcn_exp2f)
    return __builtin_amdgcn_exp2f(x);
#else
    return __expf(x * 0.69314718056f);
#endif
}

// ---------------- prep: bf16 rows scaled into log2 domain, fragment layout --
// FbP uint index for element pair (row, k=2l): (row>>4)*1024 + (l>>2)*64 +
// (row&15)*4 + (l&3). Chunk chi = l>>2 holds k = 8*chi .. 8*chi+7 in order.
// Also zeroes out[0] (stream-ordered before reduce's atomicAdd).
__global__ void prep_kernel(const float* __restrict__ F,
                            unsigned int* __restrict__ FbP,
                            float* __restrict__ out) {
    if (blockIdx.x == 0 && threadIdx.x == 0) out[0] = 0.0f;
    int row = blockIdx.x * 4 + (threadIdx.x >> 6);
    int l = threadIdx.x & 63;
    float2 v = ((const float2*)(F + (size_t)row * D))[l];
    float ss = v.x * v.x + v.y * v.y;
#pragma unroll
    for (int off = 32; off > 0; off >>= 1) ss += __shfl_xor(ss, off);
    float sc = sqrtf(14.4269504089f / ss);  // 10 * log2(e), folded
    __hip_bfloat16 hx = __float2bfloat16(v.x * sc);
    __hip_bfloat16 hy = __float2bfloat16(v.y * sc);
    unsigned int ux = *(unsigned short*)&hx;
    unsigned int uy = *(unsigned short*)&hy;
    unsigned int idx = ((unsigned)(row >> 4) << 10) | ((unsigned)(l >> 2) << 6) |
                       ((unsigned)(row & 15) << 2) | (unsigned)(l & 3);
    FbP[idx] = ux | (uy << 16);
}

// ---------------- sim: full matrix, MFMA, no LDS/barriers/atomics -----------
// 512 blocks: bid = g2 + 8*ti (XCD-bijective: all 64 blocks of col-group g2
// land on XCD g2 under bid%8 round-robin). Block (ti, g2): rows ti*128..+128
// x B-tiles tj in [8*g2, 8*g2+8). A-frags in registers, loaded ONCE for 8
// tiles; B streamed via the R15 double-buffer schedule.
#define LOADB(BUF, TJ, KK)                                          \
    _Pragma("unroll") for (int n_ = 0; n_ < 4; ++n_)                \
        BUF[n_] = P[((TJ) * 8 + wx * 4 + n_) * 256 + (KK) * 64 + l];

#define MFMASTEP(BUF, KK)                                           \
    _Pragma("unroll") for (int m_ = 0; m_ < 4; ++m_)                \
        _Pragma("unroll") for (int n_ = 0; n_ < 4; ++n_)            \
            acc[m_][n_] = __builtin_amdgcn_mfma_f32_16x16x32_bf16(  \
                Af[KK][m_], BUF[n_], acc[m_][n_], 0, 0, 0);

__global__ __launch_bounds__(256, 2) void sim_kernel(
    const short8* __restrict__ P, const int* __restrict__ labels,
    float* __restrict__ partE, float* __restrict__ partP) {
    const int g2 = blockIdx.x & 7;    // 8 column groups of 8 tiles
    const int ti = blockIdx.x >> 3;   // 64 row tiles
    const int tjs = g2 * 8;
    const int i0 = ti * 128;

    const int t = threadIdx.x, w = t >> 6, l = t & 63;
    const int c = l & 15, quad = l >> 4;    // MFMA lane split
    const int wy = w >> 1, wx = w & 1;      // 64x64 quadrant per wave

    // A fragments for the whole strip: 16 x 1KB coalesced loads, 64 VGPR.
    short8 Af[4][4];  // [kk][m]
#pragma unroll
    for (int kk = 0; kk < 4; ++kk)
#pragma unroll
        for (int m = 0; m < 4; ++m)
            Af[kk][m] = P[(ti * 8 + wy * 4 + m) * 256 + kk * 64 + l];

    // row labels for this wave's rows (strip-constant)
    int li[4][4];
#pragma unroll
    for (int m = 0; m < 4; ++m)
#pragma unroll
        for (int r = 0; r < 4; ++r)
            li[m][r] = labels[i0 + wy * 64 + m * 16 + quad * 4 + r];

    const bool selfQuad = (quad == (c >> 2));  // lane may hold self elements

    float RE[4][4] = {}, RP[4][4] = {};  // row partials, carried across strip

    short8 bfA[4], bfB[4];   // B-fragment double buffer (static indices only)
    LOADB(bfA, tjs, 0);      // prologue: kk0 and kk1 of first tile in flight
    LOADB(bfB, tjs, 1);

#pragma unroll 1
    for (int tj = tjs; tj < tjs + 8; ++tj) {
        const int j0 = tj * 128;
        int lj[4];
#pragma unroll
        for (int n = 0; n < 4; ++n) lj[n] = labels[j0 + wx * 64 + n * 16 + c];

        f32x4 acc[4][4] = {};
        const int tp = (tj < tjs + 7) ? tj + 1 : tjs;  // last prefetch harmless
        // steady state: bfA=kk0, bfB=kk1 already in flight (epilogue-covered)
        MFMASTEP(bfA, 0);
        LOADB(bfA, tj, 2);
        MFMASTEP(bfB, 1);
        LOADB(bfB, tj, 3);
        MFMASTEP(bfA, 2);
        LOADB(bfA, tp, 0);
        MFMASTEP(bfB, 3);
        LOADB(bfB, tp, 1);   // next tile's kk1 also rides under the epilogue

        // Diagonal tile: poison self elements so the clean epilogue naturally
        // zeroes them (exp2(-50)~0; the -50 entering RP is corrected at store).
        if (tj == ti && wy == wx) {
#pragma unroll
            for (int m = 0; m < 4; ++m)
#pragma unroll
                for (int r = 0; r < 4; ++r) {
                    bool cond = selfQuad && (r == (c & 3));
                    acc[m][m][r] = cond ? SELF_POISON : acc[m][m][r];
                }
        }

        // ---- minimal row-only epilogue: 5 insts per element ----
        // (covers the latency of the two next-tile prefetches above)
#pragma unroll
        for (int m = 0; m < 4; ++m) {
#pragma unroll
            for (int n = 0; n < 4; ++n) {
#pragma unroll
                for (int r = 0; r < 4; ++r) {
                    float s2 = acc[m][n][r];
                    RE[m][r] += fast_exp2(s2);
                    RP[m][r] += (li[m][r] == lj[n]) ? s2 : 0.0f;
                }
            }
        }
    }

    // strip end: row reduction across the 16 col-lanes, then PLAIN STORES to
    // this block+wave's private slice. No atomics anywhere in this kernel.
#pragma unroll
    for (int m = 0; m < 4; ++m)
#pragma unroll
        for (int r = 0; r < 4; ++r) {
#pragma unroll
            for (int off = 1; off < 16; off <<= 1) {
                RE[m][r] += __shfl_xor(RE[m][r], off);
                RP[m][r] += __shfl_xor(RP[m][r], off);
            }
        }
    if (c == 0) {
        // undo the diag poison injected into the positive-sums: exactly one
        // -50 per (m,r) row group in waves wy==wx of the diag-containing block
        // (block contains its diag tile iff ti>>3 == g2).
        if ((ti >> 3) == g2 && wy == wx) {
#pragma unroll
            for (int m = 0; m < 4; ++m)
#pragma unroll
                for (int r = 0; r < 4; ++r) RP[m][r] -= SELF_POISON;
        }
        const int slot = g2 * 2 + wx;  // 16 private slots per row
#pragma unroll
        for (int m = 0; m < 4; ++m)
#pragma unroll
            for (int r = 0; r < 4; ++r) {
                int gi = i0 + wy * 64 + m * 16 + quad * 4 + r;
                partE[(size_t)gi * 16 + slot] = RE[m][r];
                partP[(size_t)gi * 16 + slot] = RP[m][r];
            }
    }
}

// ---------------- reduce: 128 blocks; one row per 32-lane half-wave ---------
// Builds the label histogram in LDS, sums the 16 partials per row, one scaled
// atomicAdd per block into out[0].
__global__ void reduce_kernel(const float* __restrict__ partE,
                              const float* __restrict__ partP,
                              const int* __restrict__ labels,
                              float* __restrict__ out) {
    __shared__ int hist[1024];
    __shared__ float ws4[4];
    const int t = threadIdx.x, w = t >> 6, l = t & 63;
    const int half = l >> 5, sl = l & 31;
    const int rbase = blockIdx.x * 64 + w * 16;  // 64 rows/block, 16/wave

#pragma unroll
    for (int k = 0; k < 4; ++k) hist[t + 256 * k] = 0;
    __syncthreads();
#pragma unroll
    for (int k = 0; k < 32; ++k) atomicAdd(&hist[labels[t + 256 * k]], 1);
    __syncthreads();

    float a = 0.0f;
#pragma unroll
    for (int it = 0; it < 8; ++it) {
        int row = rbase + it * 2 + half;
        float se = 0.0f, sp = 0.0f;
        if (sl < 16) {
            se = partE[(size_t)row * 16 + sl];
            sp = partP[(size_t)row * 16 + sl];
        }
#pragma unroll
        for (int off = 1; off < 32; off <<= 1) {
            se += __shfl_xor(se, off);
            sp += __shfl_xor(sp, off);
        }
        if (sl == 0) {
            int cnt = hist[labels[row]] - 1;
            if (cnt > 0)
                a += logf(se + 1e-9f) - 0.69314718056f * sp / (float)cnt;
        }
    }
    // wave reduce (only lanes sl==0 carry nonzero a)
#pragma unroll
    for (int off = 1; off < 64; off <<= 1) a += __shfl_xor(a, off);
    if (l == 0) ws4[w] = a;
    __syncthreads();
    if (t == 0) {
        float s = ws4[0] + ws4[1] + ws4[2] + ws4[3];
        atomicAdd(out, s * (1.0f / (float)N));
    }
}

extern "C" void kernel_launch(void* const* d_in, const int* in_sizes, int n_in,
                              void* d_out, int out_size, void* d_ws, size_t ws_size,
                              hipStream_t stream) {
    const float* F      = (const float*)d_in[0];
    const int*   labels = (const int*)d_in[1];
    float* out = (float*)d_out;

    unsigned int* FbP = (unsigned int*)d_ws;                         // 2 MB
    float* partE = (float*)((char*)d_ws + (size_t)2 * 1024 * 1024);  // 512 KB
    float* partP = partE + (size_t)N * 16;                           // 512 KB

    prep_kernel<<<N / 4, 256, 0, stream>>>(F, FbP, out);
    sim_kernel<<<512, 256, 0, stream>>>((const short8*)FbP, labels, partE,
                                        partP);
    reduce_kernel<<<128, 256, 0, stream>>>(partE, partP, labels, out);
}